// Round 1
// baseline (277.132 us; speedup 1.0000x reference)
//
#include <hip/hip_runtime.h>
#include <stdint.h>

typedef __bf16 bf16;
typedef __bf16 bf16x8 __attribute__((ext_vector_type(8)));
typedef float f32x4 __attribute__((ext_vector_type(4)));

#define AS1 __attribute__((address_space(1)))
#define AS3 __attribute__((address_space(3)))

__device__ __forceinline__ void gload_lds16(const void* g, void* l) {
    __builtin_amdgcn_global_load_lds((const AS1 uint32_t*)g, (AS3 uint32_t*)l, 16, 0, 0);
}

// ---------------------------------------------------------------------------
// NT GEMM: C[m,n] = sum_k A[m,k]*B[n,k] + bias[n], A,B row-major bf16,
// C fp32. M,N multiples of 128, K multiple of 32.
// 256 threads = 4 waves in 2x2 grid, each wave 64x64 via 4x4 MFMA 16x16x32.
// LDS tiles staged with global_load_lds (16B/lane), XOR-swizzled k-groups
// so ds_read_b128 fragment reads are 2-way (free) instead of 8-way.
// ---------------------------------------------------------------------------
#define BM 128
#define BN 128
#define BK 32

__global__ __launch_bounds__(256, 2) void gemm_nt(
    const bf16* __restrict__ A, const bf16* __restrict__ B,
    const float* __restrict__ bias, float* __restrict__ C,
    int M, int N, int K)
{
    __shared__ bf16 smA[BM * BK];   // 8 KB
    __shared__ bf16 smB[BN * BK];   // 8 KB

    const int tid  = threadIdx.x;
    const int wave = tid >> 6;
    const int lane = tid & 63;
    const int wm = (wave >> 1) * 64;   // wave row offset in tile
    const int wn = (wave & 1) * 64;    // wave col offset in tile
    const int rowA0 = blockIdx.y * BM;
    const int rowB0 = blockIdx.x * BN;

    f32x4 acc[4][4] = {};

    const int g  = lane >> 4;      // k-group 0..3 for fragment reads
    const int rm = lane & 15;

    for (int k0 = 0; k0 < K; k0 += BK) {
        // ---- stage A and B tiles (2 issues of 256 lanes x 16B each) ----
        #pragma unroll
        for (int i = 0; i < 2; ++i) {
            int slot = i * 256 + tid;          // 512 slots of 16B per tile
            int row  = slot >> 2;              // 0..127
            int kgs  = slot & 3;               // slot k-group
            int kd   = kgs ^ ((row >> 1) & 3); // swizzled data k-group
            const bf16* ga = A + (size_t)(rowA0 + row) * K + k0 + kd * 8;
            const bf16* gb = B + (size_t)(rowB0 + row) * K + k0 + kd * 8;
            int ldsbase = (i * 256 + (wave << 6)) * 8;   // wave-uniform, elems
            gload_lds16(ga, &smA[ldsbase]);
            gload_lds16(gb, &smB[ldsbase]);
        }
        __syncthreads();

        // ---- fragments from LDS ----
        bf16x8 af[4], bfr[4];
        #pragma unroll
        for (int mi = 0; mi < 4; ++mi) {
            int row  = wm + mi * 16 + rm;
            int slot = row * 4 + (g ^ ((row >> 1) & 3));
            af[mi] = *(const bf16x8*)&smA[slot * 8];
        }
        #pragma unroll
        for (int ni = 0; ni < 4; ++ni) {
            int row  = wn + ni * 16 + rm;
            int slot = row * 4 + (g ^ ((row >> 1) & 3));
            bfr[ni] = *(const bf16x8*)&smB[slot * 8];
        }
        #pragma unroll
        for (int mi = 0; mi < 4; ++mi)
            #pragma unroll
            for (int ni = 0; ni < 4; ++ni)
                acc[mi][ni] = __builtin_amdgcn_mfma_f32_16x16x32_bf16(
                    af[mi], bfr[ni], acc[mi][ni], 0, 0, 0);
        __syncthreads();
    }

    // ---- epilogue: C/D layout col=lane&15, row=(lane>>4)*4+reg ----
    const int quad = lane >> 4;
    #pragma unroll
    for (int ni = 0; ni < 4; ++ni) {
        int col = rowB0 + wn + ni * 16 + rm;
        float bcol = bias[col];
        #pragma unroll
        for (int mi = 0; mi < 4; ++mi) {
            #pragma unroll
            for (int r = 0; r < 4; ++r) {
                int rowc = rowA0 + wm + mi * 16 + quad * 4 + r;
                C[(size_t)rowc * N + col] = acc[mi][ni][r] + bcol;
            }
        }
    }
}

// ---------------------------------------------------------------------------
// fp32 -> bf16 cast, 8 elems/thread
// ---------------------------------------------------------------------------
__global__ void cast_bf16_kernel(const float* __restrict__ in,
                                 bf16* __restrict__ out, int n8)
{
    int i = blockIdx.x * 256 + threadIdx.x;
    if (i < n8) {
        const float4* p = (const float4*)in;
        float4 a = p[2 * i], b = p[2 * i + 1];
        bf16x8 o;
        o[0] = (bf16)a.x; o[1] = (bf16)a.y; o[2] = (bf16)a.z; o[3] = (bf16)a.w;
        o[4] = (bf16)b.x; o[5] = (bf16)b.y; o[6] = (bf16)b.z; o[7] = (bf16)b.w;
        *(bf16x8*)(out + 8 * i) = o;
    }
}

// ---------------------------------------------------------------------------
// Head mixing: one block per (head, row). 128 threads = one d each.
//   c[r]    = sum_d xh[d] * Wc[h,d,r]           (block reduce)
//   s[r]    = sum_j A[h,r,j] * w[j]             (w[j] = xh at row n+j-pad)
//   t       = sum_j base[h,j,d] * w[j]
//   y[d]    = alpha * sum_r c[r]*V[h,r,d]*s[r] + (1-alpha)*t   (bf16)
// ---------------------------------------------------------------------------
__constant__ int KS_c[8] = {3, 3, 7, 7, 11, 11, 21, 21};

__global__ __launch_bounds__(128) void head_mix(
    const float* __restrict__ xp, const float* __restrict__ Wc,
    const float* __restrict__ Aw, const float* __restrict__ Vw,
    const float* __restrict__ basew, const float* __restrict__ alphas,
    bf16* __restrict__ y)
{
    const int h   = blockIdx.x;          // 0..7
    const int row = blockIdx.y;          // 0..8191 (b*4096 + n)
    const int d   = threadIdx.x;         // 0..127
    const int n   = row & 4095;
    const int k   = KS_c[h];
    const int pad = k >> 1;

    const size_t base_idx = (size_t)row * 1024 + h * 128 + d;

    // ---- c[r] via shuffle + 2-wave LDS combine ----
    float xv = xp[base_idx];
    float p0 = xv * Wc[h * 512 + d * 4 + 0];
    float p1 = xv * Wc[h * 512 + d * 4 + 1];
    float p2 = xv * Wc[h * 512 + d * 4 + 2];
    float p3 = xv * Wc[h * 512 + d * 4 + 3];
    #pragma unroll
    for (int off = 32; off > 0; off >>= 1) {
        p0 += __shfl_down(p0, off);
        p1 += __shfl_down(p1, off);
        p2 += __shfl_down(p2, off);
        p3 += __shfl_down(p3, off);
    }
    __shared__ float cpart[2][4];
    int lane = threadIdx.x & 63, wv = threadIdx.x >> 6;
    if (lane == 0) {
        cpart[wv][0] = p0; cpart[wv][1] = p1;
        cpart[wv][2] = p2; cpart[wv][3] = p3;
    }
    __syncthreads();
    float c0 = cpart[0][0] + cpart[1][0];
    float c1 = cpart[0][1] + cpart[1][1];
    float c2 = cpart[0][2] + cpart[1][2];
    float c3 = cpart[0][3] + cpart[1][3];

    // ---- convolutions ----
    float s0 = 0.f, s1 = 0.f, s2 = 0.f, s3 = 0.f, t = 0.f;
    const float* Ah = Aw + h * 84;           // A[h,r,j] at Ah[r*21+j]
    const float* bh = basew + h * 2688 + d;  // base[h,j,d] at bh[j*128]
    for (int j = 0; j < k; ++j) {
        int nn = n + j - pad;
        float w = 0.f;
        if (nn >= 0 && nn < 4096)
            w = xp[(size_t)(row + j - pad) * 1024 + h * 128 + d];
        t  += bh[j * 128] * w;
        s0 += Ah[j] * w;
        s1 += Ah[21 + j] * w;
        s2 += Ah[42 + j] * w;
        s3 += Ah[63 + j] * w;
    }

    float alpha = 1.f / (1.f + __expf(-alphas[h]));
    float o = alpha * (c0 * Vw[h * 512 + d] * s0 +
                       c1 * Vw[h * 512 + 128 + d] * s1 +
                       c2 * Vw[h * 512 + 256 + d] * s2 +
                       c3 * Vw[h * 512 + 384 + d] * s3)
            + (1.f - alpha) * t;
    y[base_idx] = (bf16)o;
}

// ---------------------------------------------------------------------------
extern "C" void kernel_launch(void* const* d_in, const int* in_sizes, int n_in,
                              void* d_out, int out_size, void* d_ws, size_t ws_size,
                              hipStream_t stream)
{
    const float* x      = (const float*)d_in[0];  // (2,4096,1024)
    const float* W_in   = (const float*)d_in[1];  // (1024,1024)
    const float* b_in   = (const float*)d_in[2];  // (1024,)
    const float* W_out  = (const float*)d_in[3];  // (1024,1024)
    const float* b_out  = (const float*)d_in[4];  // (1024,)
    const float* Wc     = (const float*)d_in[5];  // (8,128,4)
    const float* Aw     = (const float*)d_in[6];  // (8,4,21)
    const float* Vw     = (const float*)d_in[7];  // (8,4,128)
    const float* basew  = (const float*)d_in[8];  // (8,21,128)
    const float* alphas = (const float*)d_in[9];  // (8,)
    float* out = (float*)d_out;                   // (2,4096,1024) fp32

    const size_t MB = 1u << 20;
    char* ws = (char*)d_ws;
    bf16*  xb  = (bf16*) (ws);             // 16 MB: x as bf16
    bf16*  wib = (bf16*) (ws + 16 * MB);   //  2 MB: W_in bf16
    bf16*  wob = (bf16*) (ws + 18 * MB);   //  2 MB: W_out bf16
    float* xp  = (float*)(ws + 20 * MB);   // 32 MB: x_proj fp32
    bf16*  yb  = (bf16*) (ws + 52 * MB);   // 16 MB: head-concat y bf16

    const int NX = 2 * 4096 * 1024;   // 8388608
    const int NW = 1024 * 1024;       // 1048576

    cast_bf16_kernel<<<(NX / 8 + 255) / 256, 256, 0, stream>>>(x, xb, NX / 8);
    cast_bf16_kernel<<<(NW / 8 + 255) / 256, 256, 0, stream>>>(W_in, wib, NW / 8);
    cast_bf16_kernel<<<(NW / 8 + 255) / 256, 256, 0, stream>>>(W_out, wob, NW / 8);

    gemm_nt<<<dim3(1024 / BN, 8192 / BM), 256, 0, stream>>>(
        xb, wib, b_in, xp, 8192, 1024, 1024);

    head_mix<<<dim3(8, 8192), 128, 0, stream>>>(
        xp, Wc, Aw, Vw, basew, alphas, yb);

    gemm_nt<<<dim3(1024 / BN, 8192 / BM), 256, 0, stream>>>(
        yb, wob, b_out, out, 8192, 1024, 1024);
}

// Round 2
// 209.448 us; speedup vs baseline: 1.3232x; 1.3232x over previous
//
#include <hip/hip_runtime.h>
#include <stdint.h>

typedef __bf16 bf16;
typedef __bf16 bf16x8 __attribute__((ext_vector_type(8)));
typedef float f32x4 __attribute__((ext_vector_type(4)));

#define AS1 __attribute__((address_space(1)))
#define AS3 __attribute__((address_space(3)))

__device__ __forceinline__ void gload_lds16(const void* g, void* l) {
    __builtin_amdgcn_global_load_lds((const AS1 uint32_t*)g, (AS3 uint32_t*)l, 16, 0, 0);
}

// ---------------------------------------------------------------------------
// NT GEMM: C[m,n] = sum_k A[m,k]*B[n,k] + bias[n]  (unchanged from R1)
// ---------------------------------------------------------------------------
#define BM 128
#define BN 128
#define BK 32

__global__ __launch_bounds__(256, 2) void gemm_nt(
    const bf16* __restrict__ A, const bf16* __restrict__ B,
    const float* __restrict__ bias, float* __restrict__ C,
    int M, int N, int K)
{
    __shared__ bf16 smA[BM * BK];
    __shared__ bf16 smB[BN * BK];

    const int tid  = threadIdx.x;
    const int wave = tid >> 6;
    const int lane = tid & 63;
    const int wm = (wave >> 1) * 64;
    const int wn = (wave & 1) * 64;
    const int rowA0 = blockIdx.y * BM;
    const int rowB0 = blockIdx.x * BN;

    f32x4 acc[4][4] = {};

    const int g  = lane >> 4;
    const int rm = lane & 15;

    for (int k0 = 0; k0 < K; k0 += BK) {
        #pragma unroll
        for (int i = 0; i < 2; ++i) {
            int slot = i * 256 + tid;
            int row  = slot >> 2;
            int kgs  = slot & 3;
            int kd   = kgs ^ ((row >> 1) & 3);
            const bf16* ga = A + (size_t)(rowA0 + row) * K + k0 + kd * 8;
            const bf16* gb = B + (size_t)(rowB0 + row) * K + k0 + kd * 8;
            int ldsbase = (i * 256 + (wave << 6)) * 8;
            gload_lds16(ga, &smA[ldsbase]);
            gload_lds16(gb, &smB[ldsbase]);
        }
        __syncthreads();

        bf16x8 af[4], bfr[4];
        #pragma unroll
        for (int mi = 0; mi < 4; ++mi) {
            int row  = wm + mi * 16 + rm;
            int slot = row * 4 + (g ^ ((row >> 1) & 3));
            af[mi] = *(const bf16x8*)&smA[slot * 8];
        }
        #pragma unroll
        for (int ni = 0; ni < 4; ++ni) {
            int row  = wn + ni * 16 + rm;
            int slot = row * 4 + (g ^ ((row >> 1) & 3));
            bfr[ni] = *(const bf16x8*)&smB[slot * 8];
        }
        #pragma unroll
        for (int mi = 0; mi < 4; ++mi)
            #pragma unroll
            for (int ni = 0; ni < 4; ++ni)
                acc[mi][ni] = __builtin_amdgcn_mfma_f32_16x16x32_bf16(
                    af[mi], bfr[ni], acc[mi][ni], 0, 0, 0);
        __syncthreads();
    }

    const int quad = lane >> 4;
    #pragma unroll
    for (int ni = 0; ni < 4; ++ni) {
        int col = rowB0 + wn + ni * 16 + rm;
        float bcol = bias[col];
        #pragma unroll
        for (int mi = 0; mi < 4; ++mi) {
            #pragma unroll
            for (int r = 0; r < 4; ++r) {
                int rowc = rowA0 + wm + mi * 16 + quad * 4 + r;
                C[(size_t)rowc * N + col] = acc[mi][ni][r] + bcol;
            }
        }
    }
}

// ---------------------------------------------------------------------------
// fp32 -> bf16 cast, 8 elems/thread
// ---------------------------------------------------------------------------
__global__ void cast_bf16_kernel(const float* __restrict__ in,
                                 bf16* __restrict__ out, int n8)
{
    int i = blockIdx.x * 256 + threadIdx.x;
    if (i < n8) {
        const float4* p = (const float4*)in;
        float4 a = p[2 * i], b = p[2 * i + 1];
        bf16x8 o;
        o[0] = (bf16)a.x; o[1] = (bf16)a.y; o[2] = (bf16)a.z; o[3] = (bf16)a.w;
        o[4] = (bf16)b.x; o[5] = (bf16)b.y; o[6] = (bf16)b.z; o[7] = (bf16)b.w;
        *(bf16x8*)(out + 8 * i) = o;
    }
}

// ---------------------------------------------------------------------------
// c_compute: c[row,h,r] = sum_d xp[row, h*128+d] * Wc[h,d,r]
// One wave per row; lane handles 16 consecutive xp elements (head = lane>>3).
// 8-lane xor-shuffle reduce, lane (lane&7)==0 writes float4.
// ---------------------------------------------------------------------------
__global__ __launch_bounds__(256) void c_compute(
    const float* __restrict__ xp, const float* __restrict__ Wc,
    float* __restrict__ cbuf)
{
    const int wave = threadIdx.x >> 6, lane = threadIdx.x & 63;
    const int row  = blockIdx.x * 4 + wave;
    const int h    = lane >> 3;
    const int d0   = (lane & 7) * 16;

    const float4* xr = (const float4*)(xp + (size_t)row * 1024 + lane * 16);
    float p0 = 0.f, p1 = 0.f, p2 = 0.f, p3 = 0.f;
    #pragma unroll
    for (int q = 0; q < 4; ++q) {
        float4 xv = xr[q];
        float vals[4] = {xv.x, xv.y, xv.z, xv.w};
        #pragma unroll
        for (int i = 0; i < 4; ++i) {
            float4 wr = *(const float4*)(Wc + h * 512 + (d0 + q * 4 + i) * 4);
            float x = vals[i];
            p0 += x * wr.x; p1 += x * wr.y; p2 += x * wr.z; p3 += x * wr.w;
        }
    }
    #pragma unroll
    for (int off = 1; off <= 4; off <<= 1) {
        p0 += __shfl_xor(p0, off);
        p1 += __shfl_xor(p1, off);
        p2 += __shfl_xor(p2, off);
        p3 += __shfl_xor(p3, off);
    }
    if ((lane & 7) == 0) {
        float4 o = {p0, p1, p2, p3};
        *(float4*)(cbuf + (size_t)row * 32 + h * 4) = o;
    }
}

// ---------------------------------------------------------------------------
// head_mix2: register sliding-window conv. Thread owns (h, d) column and
// T=8 consecutive rows. Window w[T+K-1] in registers, fully unrolled.
//   s_r[t] = sum_j A[h,r,j]*w[t+j]; tv[t] = sum_j base[h,j,d]*w[t+j]
//   y = alpha*sum_r c[n,r]*V[r,d]*s_r + (1-alpha)*tv
// ---------------------------------------------------------------------------
__constant__ int KS_c[8] = {3, 3, 7, 7, 11, 11, 21, 21};

template <int K>
__device__ __forceinline__ void mix_body(
    int h, int d, int n0, const float* __restrict__ xp,
    const float* __restrict__ cbuf, const float* __restrict__ Aw,
    const float* __restrict__ Vw, const float* __restrict__ basew,
    float alpha, bf16* __restrict__ y)
{
    constexpr int T = 8;
    constexpr int W = T + K - 1;
    constexpr int pad = K / 2;
    const int nloc = n0 & 4095;

    float w[W];
    #pragma unroll
    for (int j = 0; j < W; ++j) {
        int nl = nloc + j - pad;
        bool valid = (nl >= 0) && (nl < 4096);
        w[j] = valid ? xp[(size_t)(n0 + j - pad) * 1024 + h * 128 + d] : 0.f;
    }

    float s0[T] = {}, s1[T] = {}, s2[T] = {}, s3[T] = {}, tv[T] = {};
    const float* Ah = Aw + h * 84;
    const float* bh = basew + h * 2688 + d;
    #pragma unroll
    for (int j = 0; j < K; ++j) {
        float a0 = Ah[j], a1 = Ah[21 + j], a2 = Ah[42 + j], a3 = Ah[63 + j];
        float bbj = bh[j * 128];
        #pragma unroll
        for (int t = 0; t < T; ++t) {
            float x = w[t + j];
            s0[t] += a0 * x; s1[t] += a1 * x;
            s2[t] += a2 * x; s3[t] += a3 * x;
            tv[t] += bbj * x;
        }
    }

    float v0 = Vw[h * 512 + d],       v1 = Vw[h * 512 + 128 + d];
    float v2 = Vw[h * 512 + 256 + d], v3 = Vw[h * 512 + 384 + d];
    #pragma unroll
    for (int t = 0; t < T; ++t) {
        float4 c4 = *(const float4*)(cbuf + (size_t)(n0 + t) * 32 + h * 4);
        float o = alpha * (c4.x * v0 * s0[t] + c4.y * v1 * s1[t] +
                           c4.z * v2 * s2[t] + c4.w * v3 * s3[t])
                + (1.f - alpha) * tv[t];
        y[(size_t)(n0 + t) * 1024 + h * 128 + d] = (bf16)o;
    }
}

__global__ __launch_bounds__(256) void head_mix2(
    const float* __restrict__ xp, const float* __restrict__ cbuf,
    const float* __restrict__ Aw, const float* __restrict__ Vw,
    const float* __restrict__ basew, const float* __restrict__ alphas,
    bf16* __restrict__ y)
{
    const int h   = blockIdx.x;
    const int d   = threadIdx.x & 127;
    const int sub = threadIdx.x >> 7;
    const int n0  = (blockIdx.y * 2 + sub) * 8;
    const float alpha = 1.f / (1.f + __expf(-alphas[h]));

    switch (KS_c[h]) {
        case 3:  mix_body<3>(h, d, n0, xp, cbuf, Aw, Vw, basew, alpha, y); break;
        case 7:  mix_body<7 >(h, d, n0, xp, cbuf, Aw, Vw, basew, alpha, y); break;
        case 11: mix_body<11>(h, d, n0, xp, cbuf, Aw, Vw, basew, alpha, y); break;
        default: mix_body<21>(h, d, n0, xp, cbuf, Aw, Vw, basew, alpha, y); break;
    }
}

// ---------------------------------------------------------------------------
extern "C" void kernel_launch(void* const* d_in, const int* in_sizes, int n_in,
                              void* d_out, int out_size, void* d_ws, size_t ws_size,
                              hipStream_t stream)
{
    const float* x      = (const float*)d_in[0];
    const float* W_in   = (const float*)d_in[1];
    const float* b_in   = (const float*)d_in[2];
    const float* W_out  = (const float*)d_in[3];
    const float* b_out  = (const float*)d_in[4];
    const float* Wc     = (const float*)d_in[5];
    const float* Aw     = (const float*)d_in[6];
    const float* Vw     = (const float*)d_in[7];
    const float* basew  = (const float*)d_in[8];
    const float* alphas = (const float*)d_in[9];
    float* out = (float*)d_out;

    const size_t MB = 1u << 20;
    char* ws = (char*)d_ws;
    bf16*  xb   = (bf16*) (ws);             // 16 MB
    bf16*  wib  = (bf16*) (ws + 16 * MB);   //  2 MB
    bf16*  wob  = (bf16*) (ws + 18 * MB);   //  2 MB
    float* xp   = (float*)(ws + 20 * MB);   // 32 MB
    bf16*  yb   = (bf16*) (ws + 52 * MB);   // 16 MB
    float* cbuf = (float*)(ws + 68 * MB);   //  1 MB

    const int NX = 2 * 4096 * 1024;
    const int NW = 1024 * 1024;

    cast_bf16_kernel<<<(NX / 8 + 255) / 256, 256, 0, stream>>>(x, xb, NX / 8);
    cast_bf16_kernel<<<(NW / 8 + 255) / 256, 256, 0, stream>>>(W_in, wib, NW / 8);
    cast_bf16_kernel<<<(NW / 8 + 255) / 256, 256, 0, stream>>>(W_out, wob, NW / 8);

    gemm_nt<<<dim3(1024 / BN, 8192 / BM), 256, 0, stream>>>(
        xb, wib, b_in, xp, 8192, 1024, 1024);

    c_compute<<<8192 / 4, 256, 0, stream>>>(xp, Wc, cbuf);

    head_mix2<<<dim3(8, 512), 256, 0, stream>>>(
        xp, cbuf, Aw, Vw, basew, alphas, yb);

    gemm_nt<<<dim3(1024 / BN, 8192 / BM), 256, 0, stream>>>(
        yb, wob, b_out, out, 8192, 1024, 1024);
}

// Round 3
// 200.651 us; speedup vs baseline: 1.3812x; 1.0438x over previous
//
#include <hip/hip_runtime.h>
#include <stdint.h>

typedef __bf16 bf16;
typedef __bf16 bf16x8 __attribute__((ext_vector_type(8)));
typedef float f32x4 __attribute__((ext_vector_type(4)));

#define AS1 __attribute__((address_space(1)))
#define AS3 __attribute__((address_space(3)))

__device__ __forceinline__ void gload_lds16(const void* g, void* l) {
    __builtin_amdgcn_global_load_lds((const AS1 uint32_t*)g, (AS3 uint32_t*)l, 16, 0, 0);
}

// ---------------------------------------------------------------------------
// NT GEMM: C[m,n] = sum_k A[m,k]*B[n,k] + bias[n], A,B row-major bf16.
// Grid: (M/BM, N/BN) — blockIdx.x = A-row tile so the 8 blocks sharing an
// A tile (varying blockIdx.y) land on the SAME XCD (round-robin id % 8),
// giving XCD-local L2 reuse of A. B (2 MB) is L2-resident everywhere.
// ---------------------------------------------------------------------------
#define BM 128
#define BN 128
#define BK 32

__global__ __launch_bounds__(256, 2) void gemm_nt(
    const bf16* __restrict__ A, const bf16* __restrict__ B,
    const float* __restrict__ bias, float* __restrict__ C,
    int M, int N, int K)
{
    __shared__ bf16 smA[BM * BK];
    __shared__ bf16 smB[BN * BK];

    const int tid  = threadIdx.x;
    const int wave = tid >> 6;
    const int lane = tid & 63;
    const int wm = (wave >> 1) * 64;
    const int wn = (wave & 1) * 64;
    const int rowA0 = blockIdx.x * BM;   // M tile (XCD-local reuse)
    const int rowB0 = blockIdx.y * BN;   // N tile

    f32x4 acc[4][4] = {};

    const int g  = lane >> 4;
    const int rm = lane & 15;

    for (int k0 = 0; k0 < K; k0 += BK) {
        #pragma unroll
        for (int i = 0; i < 2; ++i) {
            int slot = i * 256 + tid;
            int row  = slot >> 2;
            int kgs  = slot & 3;
            int kd   = kgs ^ ((row >> 1) & 3);
            const bf16* ga = A + (size_t)(rowA0 + row) * K + k0 + kd * 8;
            const bf16* gb = B + (size_t)(rowB0 + row) * K + k0 + kd * 8;
            int ldsbase = (i * 256 + (wave << 6)) * 8;
            gload_lds16(ga, &smA[ldsbase]);
            gload_lds16(gb, &smB[ldsbase]);
        }
        __syncthreads();

        bf16x8 af[4], bfr[4];
        #pragma unroll
        for (int mi = 0; mi < 4; ++mi) {
            int row  = wm + mi * 16 + rm;
            int slot = row * 4 + (g ^ ((row >> 1) & 3));
            af[mi] = *(const bf16x8*)&smA[slot * 8];
        }
        #pragma unroll
        for (int ni = 0; ni < 4; ++ni) {
            int row  = wn + ni * 16 + rm;
            int slot = row * 4 + (g ^ ((row >> 1) & 3));
            bfr[ni] = *(const bf16x8*)&smB[slot * 8];
        }
        #pragma unroll
        for (int mi = 0; mi < 4; ++mi)
            #pragma unroll
            for (int ni = 0; ni < 4; ++ni)
                acc[mi][ni] = __builtin_amdgcn_mfma_f32_16x16x32_bf16(
                    af[mi], bfr[ni], acc[mi][ni], 0, 0, 0);
        __syncthreads();
    }

    const int quad = lane >> 4;
    #pragma unroll
    for (int ni = 0; ni < 4; ++ni) {
        int col = rowB0 + wn + ni * 16 + rm;
        float bcol = bias[col];
        #pragma unroll
        for (int mi = 0; mi < 4; ++mi) {
            #pragma unroll
            for (int r = 0; r < 4; ++r) {
                int rowc = rowA0 + wm + mi * 16 + quad * 4 + r;
                C[(size_t)rowc * N + col] = acc[mi][ni][r] + bcol;
            }
        }
    }
}

// ---------------------------------------------------------------------------
// fused fp32 -> bf16 cast of x, W_in, W_out (one launch)
// ---------------------------------------------------------------------------
__global__ void cast_all_kernel(const float* __restrict__ x, bf16* __restrict__ xb,
                                const float* __restrict__ wi, bf16* __restrict__ wib,
                                const float* __restrict__ wo, bf16* __restrict__ wob)
{
    const int NX8 = (2 * 4096 * 1024) / 8;   // 1048576
    const int NW8 = (1024 * 1024) / 8;       // 131072
    int i = blockIdx.x * 256 + threadIdx.x;  // 0 .. NX8+2*NW8-1
    const float* in; bf16* out; int idx;
    if (i < NX8)            { in = x;  out = xb;  idx = i; }
    else if (i < NX8 + NW8) { in = wi; out = wib; idx = i - NX8; }
    else                    { in = wo; out = wob; idx = i - NX8 - NW8; }
    const float4* p = (const float4*)in;
    float4 a = p[2 * idx], b = p[2 * idx + 1];
    bf16x8 o;
    o[0] = (bf16)a.x; o[1] = (bf16)a.y; o[2] = (bf16)a.z; o[3] = (bf16)a.w;
    o[4] = (bf16)b.x; o[5] = (bf16)b.y; o[6] = (bf16)b.z; o[7] = (bf16)b.w;
    *(bf16x8*)(out + 8 * idx) = o;
}

// ---------------------------------------------------------------------------
// c_compute: c[row,h,r] = sum_d xp[row, h*128+d] * Wc[h,d,r]
// ---------------------------------------------------------------------------
__global__ __launch_bounds__(256) void c_compute(
    const float* __restrict__ xp, const float* __restrict__ Wc,
    float* __restrict__ cbuf)
{
    const int wave = threadIdx.x >> 6, lane = threadIdx.x & 63;
    const int row  = blockIdx.x * 4 + wave;
    const int h    = lane >> 3;
    const int d0   = (lane & 7) * 16;

    const float4* xr = (const float4*)(xp + (size_t)row * 1024 + lane * 16);
    float p0 = 0.f, p1 = 0.f, p2 = 0.f, p3 = 0.f;
    #pragma unroll
    for (int q = 0; q < 4; ++q) {
        float4 xv = xr[q];
        float vals[4] = {xv.x, xv.y, xv.z, xv.w};
        #pragma unroll
        for (int i = 0; i < 4; ++i) {
            float4 wr = *(const float4*)(Wc + h * 512 + (d0 + q * 4 + i) * 4);
            float x = vals[i];
            p0 += x * wr.x; p1 += x * wr.y; p2 += x * wr.z; p3 += x * wr.w;
        }
    }
    #pragma unroll
    for (int off = 1; off <= 4; off <<= 1) {
        p0 += __shfl_xor(p0, off);
        p1 += __shfl_xor(p1, off);
        p2 += __shfl_xor(p2, off);
        p3 += __shfl_xor(p3, off);
    }
    if ((lane & 7) == 0) {
        float4 o = {p0, p1, p2, p3};
        *(float4*)(cbuf + (size_t)row * 32 + h * 4) = o;
    }
}

// ---------------------------------------------------------------------------
// head_mix2: register sliding-window conv (unchanged from R2)
// ---------------------------------------------------------------------------
__constant__ int KS_c[8] = {3, 3, 7, 7, 11, 11, 21, 21};

template <int K>
__device__ __forceinline__ void mix_body(
    int h, int d, int n0, const float* __restrict__ xp,
    const float* __restrict__ cbuf, const float* __restrict__ Aw,
    const float* __restrict__ Vw, const float* __restrict__ basew,
    float alpha, bf16* __restrict__ y)
{
    constexpr int T = 8;
    constexpr int W = T + K - 1;
    constexpr int pad = K / 2;
    const int nloc = n0 & 4095;

    float w[W];
    #pragma unroll
    for (int j = 0; j < W; ++j) {
        int nl = nloc + j - pad;
        bool valid = (nl >= 0) && (nl < 4096);
        w[j] = valid ? xp[(size_t)(n0 + j - pad) * 1024 + h * 128 + d] : 0.f;
    }

    float s0[T] = {}, s1[T] = {}, s2[T] = {}, s3[T] = {}, tv[T] = {};
    const float* Ah = Aw + h * 84;
    const float* bh = basew + h * 2688 + d;
    #pragma unroll
    for (int j = 0; j < K; ++j) {
        float a0 = Ah[j], a1 = Ah[21 + j], a2 = Ah[42 + j], a3 = Ah[63 + j];
        float bbj = bh[j * 128];
        #pragma unroll
        for (int t = 0; t < T; ++t) {
            float x = w[t + j];
            s0[t] += a0 * x; s1[t] += a1 * x;
            s2[t] += a2 * x; s3[t] += a3 * x;
            tv[t] += bbj * x;
        }
    }

    float v0 = Vw[h * 512 + d],       v1 = Vw[h * 512 + 128 + d];
    float v2 = Vw[h * 512 + 256 + d], v3 = Vw[h * 512 + 384 + d];
    #pragma unroll
    for (int t = 0; t < T; ++t) {
        float4 c4 = *(const float4*)(cbuf + (size_t)(n0 + t) * 32 + h * 4);
        float o = alpha * (c4.x * v0 * s0[t] + c4.y * v1 * s1[t] +
                           c4.z * v2 * s2[t] + c4.w * v3 * s3[t])
                + (1.f - alpha) * tv[t];
        y[(size_t)(n0 + t) * 1024 + h * 128 + d] = (bf16)o;
    }
}

__global__ __launch_bounds__(256) void head_mix2(
    const float* __restrict__ xp, const float* __restrict__ cbuf,
    const float* __restrict__ Aw, const float* __restrict__ Vw,
    const float* __restrict__ basew, const float* __restrict__ alphas,
    bf16* __restrict__ y)
{
    const int h   = blockIdx.x;
    const int d   = threadIdx.x & 127;
    const int sub = threadIdx.x >> 7;
    const int n0  = (blockIdx.y * 2 + sub) * 8;
    const float alpha = 1.f / (1.f + __expf(-alphas[h]));

    switch (KS_c[h]) {
        case 3:  mix_body<3>(h, d, n0, xp, cbuf, Aw, Vw, basew, alpha, y); break;
        case 7:  mix_body<7 >(h, d, n0, xp, cbuf, Aw, Vw, basew, alpha, y); break;
        case 11: mix_body<11>(h, d, n0, xp, cbuf, Aw, Vw, basew, alpha, y); break;
        default: mix_body<21>(h, d, n0, xp, cbuf, Aw, Vw, basew, alpha, y); break;
    }
}

// ---------------------------------------------------------------------------
extern "C" void kernel_launch(void* const* d_in, const int* in_sizes, int n_in,
                              void* d_out, int out_size, void* d_ws, size_t ws_size,
                              hipStream_t stream)
{
    const float* x      = (const float*)d_in[0];
    const float* W_in   = (const float*)d_in[1];
    const float* b_in   = (const float*)d_in[2];
    const float* W_out  = (const float*)d_in[3];
    const float* b_out  = (const float*)d_in[4];
    const float* Wc     = (const float*)d_in[5];
    const float* Aw     = (const float*)d_in[6];
    const float* Vw     = (const float*)d_in[7];
    const float* basew  = (const float*)d_in[8];
    const float* alphas = (const float*)d_in[9];
    float* out = (float*)d_out;

    const size_t MB = 1u << 20;
    char* ws = (char*)d_ws;
    bf16*  xb   = (bf16*) (ws);             // 16 MB
    bf16*  wib  = (bf16*) (ws + 16 * MB);   //  2 MB
    bf16*  wob  = (bf16*) (ws + 18 * MB);   //  2 MB
    float* xp   = (float*)(ws + 20 * MB);   // 32 MB
    bf16*  yb   = (bf16*) (ws + 52 * MB);   // 16 MB
    float* cbuf = (float*)(ws + 68 * MB);   //  1 MB

    const int NTOT8 = (2 * 4096 * 1024 + 2 * 1024 * 1024) / 8;  // casts total

    cast_all_kernel<<<NTOT8 / 256, 256, 0, stream>>>(x, xb, W_in, wib, W_out, wob);

    gemm_nt<<<dim3(8192 / BM, 1024 / BN), 256, 0, stream>>>(
        xb, wib, b_in, xp, 8192, 1024, 1024);

    c_compute<<<8192 / 4, 256, 0, stream>>>(xp, Wc, cbuf);

    head_mix2<<<dim3(8, 512), 256, 0, stream>>>(
        xp, cbuf, Aw, Vw, basew, alphas, yb);

    gemm_nt<<<dim3(8192 / BM, 1024 / BN), 256, 0, stream>>>(
        yb, wob, b_out, out, 8192, 1024, 1024);
}